// Round 5
// baseline (143.427 us; speedup 1.0000x reference)
//
#include <hip/hip_runtime.h>
#include <hip/hip_fp16.h>

typedef _Float16 half8  __attribute__((ext_vector_type(8)));
typedef _Float16 half4v __attribute__((ext_vector_type(4)));
typedef float    f32x4  __attribute__((ext_vector_type(4)));

#define MFMA_F16 __builtin_amdgcn_mfma_f32_16x16x32_f16

// ---------------- kernel 0: W_q|W_k|W_v f32 -> concat f16 [384][1024] ----------------
__global__ __launch_bounds__(256) void wconv_k(const float* __restrict__ wq,
                                               const float* __restrict__ wk,
                                               const float* __restrict__ wv,
                                               _Float16* __restrict__ wh) {
    int i = (blockIdx.x * 256 + threadIdx.x) * 8;   // 393216 total elems
    const float* src; int off;
    if (i < 131072)      { src = wq; off = i; }
    else if (i < 262144) { src = wk; off = i - 131072; }
    else                 { src = wv; off = i - 262144; }
    float4 a = *(const float4*)(src + off);
    float4 b = *(const float4*)(src + off + 4);
    half8 h;
    h[0]=(_Float16)a.x; h[1]=(_Float16)a.y; h[2]=(_Float16)a.z; h[3]=(_Float16)a.w;
    h[4]=(_Float16)b.x; h[5]=(_Float16)b.y; h[6]=(_Float16)b.z; h[7]=(_Float16)b.w;
    *(half8*)(wh + i) = h;
}

// ---------------- kernel 1: fused QKV projection ----------------
// grid 512: rb=bid>>1 (64-row group), cb=bid&1 (192-col half). 256 thr = 4 waves.
__global__ __launch_bounds__(256, 2) void qkv_k(const float* __restrict__ x,
                                                const _Float16* __restrict__ wh,
                                                _Float16* __restrict__ qh,
                                                _Float16* __restrict__ kh,
                                                _Float16* __restrict__ vth) {
    __shared__ _Float16 xs[2][64 * 136];
    const int tid = threadIdx.x;
    const int w = tid >> 6, l = tid & 63;
    const int fr = l & 15, fq = l >> 4;
    const int rb = blockIdx.x >> 1, cb = blockIdx.x & 1;
    const int row0 = rb * 64;
    const int c0 = cb * 192 + w * 48;

    const int srow = tid >> 2, sg = tid & 3;
    const float* xg = x + (row0 + srow) * 1024 + sg * 4;
    const _Float16* wgb = wh + (c0 + fr) * 1024 + fq * 8;

    f32x4 acc[4][3] = {};
    float4 xa[8];
    half8 wf[2][3];

#pragma unroll
    for (int i = 0; i < 8; ++i) xa[i] = *(const float4*)(xg + i * 16);
#pragma unroll
    for (int i = 0; i < 8; ++i) {
        float4 t = xa[i]; half4v hv;
        hv[0]=(_Float16)t.x; hv[1]=(_Float16)t.y; hv[2]=(_Float16)t.z; hv[3]=(_Float16)t.w;
        *(half4v*)(&xs[0][srow * 136 + sg * 4 + i * 16]) = hv;
    }
#pragma unroll
    for (int i = 0; i < 8; ++i) xa[i] = *(const float4*)(xg + 128 + i * 16);
#pragma unroll
    for (int nf = 0; nf < 3; ++nf) wf[0][nf] = *(const half8*)(wgb + nf * 16384);
    __syncthreads();

    int cur = 0;
    for (int kt = 0; kt < 8; ++kt) {
        if (kt < 7) {
#pragma unroll
            for (int i = 0; i < 8; ++i) {
                float4 t = xa[i]; half4v hv;
                hv[0]=(_Float16)t.x; hv[1]=(_Float16)t.y; hv[2]=(_Float16)t.z; hv[3]=(_Float16)t.w;
                *(half4v*)(&xs[cur ^ 1][srow * 136 + sg * 4 + i * 16]) = hv;
            }
            if (kt < 6) {
#pragma unroll
                for (int i = 0; i < 8; ++i)
                    xa[i] = *(const float4*)(xg + (kt + 2) * 128 + i * 16);
            }
        }
#pragma unroll
        for (int s = 0; s < 4; ++s) {
            const int ss = kt * 4 + s;
            const int csw = ss & 1;
            if (ss + 1 < 32) {
#pragma unroll
                for (int nf = 0; nf < 3; ++nf)
                    wf[csw ^ 1][nf] = *(const half8*)(wgb + nf * 16384 + (ss + 1) * 32);
            }
            half8 af[4];
#pragma unroll
            for (int mf = 0; mf < 4; ++mf)
                af[mf] = *(const half8*)(&xs[cur][(mf * 16 + fr) * 136 + s * 32 + fq * 8]);
#pragma unroll
            for (int mf = 0; mf < 4; ++mf)
#pragma unroll
                for (int nf = 0; nf < 3; ++nf)
                    acc[mf][nf] = MFMA_F16(af[mf], wf[csw][nf], acc[mf][nf], 0, 0, 0);
        }
        __syncthreads();
        cur ^= 1;
    }

#pragma unroll
    for (int nf = 0; nf < 3; ++nf) {
        int n0 = c0 + nf * 16 + fr;
#pragma unroll
        for (int mf = 0; mf < 4; ++mf) {
            int mb = row0 + mf * 16 + fq * 4;
            if (n0 < 128) {
#pragma unroll
                for (int r = 0; r < 4; ++r) qh[(mb + r) * 128 + n0] = (_Float16)acc[mf][nf][r];
            } else if (n0 < 256) {
#pragma unroll
                for (int r = 0; r < 4; ++r) kh[(mb + r) * 128 + (n0 - 128)] = (_Float16)acc[mf][nf][r];
            } else {
                half4v pv;
#pragma unroll
                for (int r = 0; r < 4; ++r) pv[r] = (_Float16)acc[mf][nf][r];
                *(half4v*)(&vth[((mb >> 11) * 128 + (n0 - 256)) * 2048 + (mb & 2047)]) = pv;
            }
        }
    }
}

// ---------------- kernel 2: causal flash attention, split-KV, barrier-free ----------------
// 640 blocks x 256 threads = 4 INDEPENDENT waves. K/V read directly from L2 (1 MB/batch,
// pinned per-XCD via b = bid&7). No __syncthreads anywhere; only per-wave P LDS buffer.
__global__ __launch_bounds__(256, 4) void attn_k(const _Float16* __restrict__ qh,
                                                 const _Float16* __restrict__ kh,
                                                 const _Float16* __restrict__ vth,
                                                 _Float16* __restrict__ part,
                                                 float* __restrict__ stats,
                                                 float* __restrict__ out) {
    __shared__ _Float16 ps[64 * 72];   // per-wave 16-row P slices

    int bid = blockIdx.x;
    int b = bid & 7;
    int u = bid >> 3;
    int qt, c;
    if (u < 8)       { qt = u;                  c = 0; }
    else if (u < 24) { qt = 8  + ((u - 8) >> 1);  c = (u - 8) & 1; }
    else if (u < 48) { qt = 16 + (u - 24) / 3;    c = (u - 24) % 3; }
    else             { qt = 24 + ((u - 48) >> 2); c = (u - 48) & 3; }
    int j0 = c * 8;
    int j1 = j0 + 8 < qt + 1 ? j0 + 8 : qt + 1;

    int tid = threadIdx.x, w = tid >> 6, l = tid & 63;
    int fr = l & 15, fq = l >> 4;

    half8 qf[4];
    const _Float16* qp = qh + ((b * 2048 + qt * 64 + w * 16 + fr) << 7);
#pragma unroll
    for (int cc = 0; cc < 4; ++cc) qf[cc] = *(const half8*)(qp + cc * 32 + fq * 8);

    // K fragment base: row (j*64 + n*16 + fr), elems cc*32 + fq*8
    const _Float16* kb = kh + (((b << 11) + fr) << 7) + fq * 8;
    // V fragment base: vth[b][d=dt*16+fr][j*64 + c2*32 + fq*8]
    const _Float16* vb = vth + (((b << 7) + fr) << 11) + fq * 8;

    f32x4 acc[8] = {};
    float mrow[4], lrow[4];
#pragma unroll
    for (int r = 0; r < 4; ++r) { mrow[r] = -1e30f; lrow[r] = 0.0f; }

    for (int j = j0; j < j1; ++j) {
        // ---- S = Q K^T, K frags straight from L2 ----
        f32x4 s[4] = {};
#pragma unroll
        for (int n = 0; n < 4; ++n) {
            half8 kf[4];
#pragma unroll
            for (int cc = 0; cc < 4; ++cc)
                kf[cc] = *(const half8*)(kb + (((j << 6) + n * 16) << 7) + cc * 32);
#pragma unroll
            for (int cc = 0; cc < 4; ++cc)
                s[n] = MFMA_F16(qf[cc], kf[cc], s[n], 0, 0, 0);
        }
        const float sc = 0.088388347648318447f;  // 1/sqrt(128)
        if (j == qt) {
#pragma unroll
            for (int n = 0; n < 4; ++n)
#pragma unroll
                for (int r = 0; r < 4; ++r) {
                    int qrow = w * 16 + fq * 4 + r;
                    int kcol = n * 16 + fr;
                    float v = s[n][r] * sc;
                    s[n][r] = (kcol > qrow) ? -1e30f : v;
                }
        } else {
#pragma unroll
            for (int n = 0; n < 4; ++n)
#pragma unroll
                for (int r = 0; r < 4; ++r) s[n][r] *= sc;
        }

        // ---- online softmax (16-lane row groups) ----
        float mx[4];
#pragma unroll
        for (int r = 0; r < 4; ++r)
            mx[r] = fmaxf(fmaxf(s[0][r], s[1][r]), fmaxf(s[2][r], s[3][r]));
#pragma unroll
        for (int off = 1; off < 16; off <<= 1)
#pragma unroll
            for (int r = 0; r < 4; ++r) mx[r] = fmaxf(mx[r], __shfl_xor(mx[r], off));
        float al[4];
#pragma unroll
        for (int r = 0; r < 4; ++r) {
            float nm = fmaxf(mrow[r], mx[r]);
            al[r] = __expf(mrow[r] - nm);
            mrow[r] = nm;
        }
        float rs[4] = {0.f, 0.f, 0.f, 0.f};
#pragma unroll
        for (int n = 0; n < 4; ++n)
#pragma unroll
            for (int r = 0; r < 4; ++r) {
                float p = __expf(s[n][r] - mrow[r]);
                s[n][r] = p;
                rs[r] += p;
            }
#pragma unroll
        for (int off = 1; off < 16; off <<= 1)
#pragma unroll
            for (int r = 0; r < 4; ++r) rs[r] += __shfl_xor(rs[r], off);
#pragma unroll
        for (int r = 0; r < 4; ++r) lrow[r] = lrow[r] * al[r] + rs[r];
#pragma unroll
        for (int dt = 0; dt < 8; ++dt)
#pragma unroll
            for (int r = 0; r < 4; ++r) acc[dt][r] *= al[r];

        // ---- P -> per-wave LDS slice (no cross-wave sharing) ----
#pragma unroll
        for (int n = 0; n < 4; ++n)
#pragma unroll
            for (int r = 0; r < 4; ++r)
                ps[(w * 16 + fq * 4 + r) * 72 + n * 16 + fr] = (_Float16)s[n][r];

        half8 pa[2];
#pragma unroll
        for (int c2 = 0; c2 < 2; ++c2)
            pa[c2] = *(const half8*)(&ps[(w * 16 + fr) * 72 + c2 * 32 + fq * 8]);

        // ---- PV, V frags straight from L2 ----
#pragma unroll
        for (int dt = 0; dt < 8; ++dt) {
#pragma unroll
            for (int c2 = 0; c2 < 2; ++c2) {
                half8 vf = *(const half8*)(vb + ((dt * 16) << 11) + (j << 6) + c2 * 32);
                acc[dt] = MFMA_F16(pa[c2], vf, acc[dt], 0, 0, 0);
            }
        }
    }

    float inv[4];
#pragma unroll
    for (int r = 0; r < 4; ++r) inv[r] = 1.0f / lrow[r];

    if (qt < 8) {
        float* op = out + ((b * 2048 + qt * 64 + w * 16 + fq * 4) << 7) + fr;
#pragma unroll
        for (int dt = 0; dt < 8; ++dt)
#pragma unroll
            for (int r = 0; r < 4; ++r)
                op[r * 128 + dt * 16] = acc[dt][r] * inv[r];
    } else {
        // permuted lane-contiguous partial: part[bid][w][dt][r][fq][fr]
        _Float16* op = part + bid * 8192 + w * 2048 + fq * 16 + fr;
#pragma unroll
        for (int dt = 0; dt < 8; ++dt)
#pragma unroll
            for (int r = 0; r < 4; ++r)
                op[dt * 256 + r * 64] = (_Float16)(acc[dt][r] * inv[r]);
        if (fr == 0) {
#pragma unroll
            for (int r = 0; r < 4; ++r) {
                int ridx = bid * 64 + w * 16 + fq * 4 + r;
                stats[ridx * 2]     = mrow[r];
                stats[ridx * 2 + 1] = lrow[r];
            }
        }
    }
}

// ---------------- kernel 3: combine split-KV partials (qt >= 8 only) ----------------
__global__ __launch_bounds__(256) void comb_k(const _Float16* __restrict__ part,
                                              const float* __restrict__ stats,
                                              float* __restrict__ out) {
    int bid = blockIdx.x;
    int b = bid & 7, qt = 8 + (bid >> 3);
    int u0 = qt < 16 ? 8 + 2 * (qt - 8) : qt < 24 ? 24 + 3 * (qt - 16) : 48 + 4 * (qt - 24);
    int nc = qt < 16 ? 2 : qt < 24 ? 3 : 4;
    int t = threadIdx.x;
    int row = t >> 2, g = t & 3;
    int w = row >> 4, fq = (row >> 2) & 3, r = row & 3;

    float mstar = -1e30f, mv[4], lv[4];
#pragma unroll
    for (int cc = 0; cc < 4; ++cc) {
        if (cc < nc) {
            int sidx = (((u0 + cc) << 3) + b) * 64 + row;
            mv[cc] = stats[sidx * 2];
            lv[cc] = stats[sidx * 2 + 1];
            mstar = fmaxf(mstar, mv[cc]);
        }
    }
    float den = 0.f, wc[4];
#pragma unroll
    for (int cc = 0; cc < 4; ++cc) {
        if (cc < nc) { wc[cc] = __expf(mv[cc] - mstar) * lv[cc]; den += wc[cc]; }
        else wc[cc] = 0.f;
    }
    float a[32] = {};
#pragma unroll
    for (int cc = 0; cc < 4; ++cc) {
        if (cc < nc) {
            const _Float16* pp = part + ((((u0 + cc) << 3) + b) * 8192)
                                 + w * 2048 + r * 64 + fq * 16;
            float wcc = wc[cc];
#pragma unroll
            for (int dd = 0; dd < 2; ++dd) {
                half8 h0 = *(const half8*)(pp + (2 * g + dd) * 256);
                half8 h1 = *(const half8*)(pp + (2 * g + dd) * 256 + 8);
#pragma unroll
                for (int e = 0; e < 8; ++e) {
                    a[dd * 16 + e]     += wcc * (float)h0[e];
                    a[dd * 16 + 8 + e] += wcc * (float)h1[e];
                }
            }
        }
    }
    float id = 1.0f / den;
    float* op = out + (b * 2048 + qt * 64 + row) * 128 + g * 32;
#pragma unroll
    for (int uu = 0; uu < 8; ++uu) {
        float4 o;
        o.x = a[uu * 4]     * id;
        o.y = a[uu * 4 + 1] * id;
        o.z = a[uu * 4 + 2] * id;
        o.w = a[uu * 4 + 3] * id;
        *(float4*)(op + uu * 4) = o;
    }
}

extern "C" void kernel_launch(void* const* d_in, const int* in_sizes, int n_in,
                              void* d_out, int out_size, void* d_ws, size_t ws_size,
                              hipStream_t stream) {
    const float* x  = (const float*)d_in[0];
    const float* wq = (const float*)d_in[1];
    const float* wk = (const float*)d_in[2];
    const float* wv = (const float*)d_in[3];

    char* ws = (char*)d_ws;
    _Float16* wh   = (_Float16*)(ws);                    // 768 KB
    _Float16* qhp  = (_Float16*)(ws + (1u  << 20));      // 4 MB
    _Float16* khp  = (_Float16*)(ws + (5u  << 20));      // 4 MB
    _Float16* vtp  = (_Float16*)(ws + (9u  << 20));      // 4 MB
    _Float16* part = (_Float16*)(ws + (13u << 20));      // 640*16KB = 10.5 MB
    float*    stat = (float*)   (ws + (24u << 20));      // 328 KB

    wconv_k<<<192, 256, 0, stream>>>(wq, wk, wv, wh);
    qkv_k<<<512, 256, 0, stream>>>(x, wh, qhp, khp, vtp);
    attn_k<<<640, 256, 0, stream>>>(qhp, khp, vtp, part, stat, (float*)d_out);
    comb_k<<<192, 256, 0, stream>>>(part, stat, (float*)d_out);
}

// Round 6
// 143.131 us; speedup vs baseline: 1.0021x; 1.0021x over previous
//
#include <hip/hip_runtime.h>
#include <hip/hip_fp16.h>

typedef _Float16 half8  __attribute__((ext_vector_type(8)));
typedef _Float16 half4v __attribute__((ext_vector_type(4)));
typedef float    f32x4  __attribute__((ext_vector_type(4)));

#define MFMA_F16 __builtin_amdgcn_mfma_f32_16x16x32_f16

// ---------------- kernel 0: W_q|W_k|W_v f32 -> concat f16 [384][1024] ----------------
__global__ __launch_bounds__(256) void wconv_k(const float* __restrict__ wq,
                                               const float* __restrict__ wk,
                                               const float* __restrict__ wv,
                                               _Float16* __restrict__ wh) {
    int i = (blockIdx.x * 256 + threadIdx.x) * 8;
    const float* src; int off;
    if (i < 131072)      { src = wq; off = i; }
    else if (i < 262144) { src = wk; off = i - 131072; }
    else                 { src = wv; off = i - 262144; }
    float4 a = *(const float4*)(src + off);
    float4 b = *(const float4*)(src + off + 4);
    half8 h;
    h[0]=(_Float16)a.x; h[1]=(_Float16)a.y; h[2]=(_Float16)a.z; h[3]=(_Float16)a.w;
    h[4]=(_Float16)b.x; h[5]=(_Float16)b.y; h[6]=(_Float16)b.z; h[7]=(_Float16)b.w;
    *(half8*)(wh + i) = h;
}

// ---------------- kernel 1: fused QKV projection ----------------
// grid 1024: rb=bid>>1 (32-row tile), cb=bid&1 (192-col half). 4 waves; wave: 32r x 48c.
// K-step 128, double-buffered LDS, reg prefetch. 4 blocks/CU.
__global__ __launch_bounds__(256, 4) void qkv_k(const float* __restrict__ x,
                                                const _Float16* __restrict__ wh,
                                                _Float16* __restrict__ qh,
                                                _Float16* __restrict__ kh,
                                                _Float16* __restrict__ vth) {
    __shared__ _Float16 xs[2][32 * 136];
    const int tid = threadIdx.x;
    const int w = tid >> 6, l = tid & 63;
    const int fr = l & 15, fq = l >> 4;
    const int rb = blockIdx.x >> 1, cb = blockIdx.x & 1;
    const int row0 = rb * 32;
    const int c0 = cb * 192 + w * 48;

    const int srow = tid >> 3, sg = tid & 7;
    const float* xg = x + (row0 + srow) * 1024 + sg * 4;
    const _Float16* wgb = wh + (c0 + fr) * 1024 + fq * 8;

    f32x4 acc[2][3] = {};
    float4 xa[4];
    half8 wf[2][3];

#pragma unroll
    for (int i = 0; i < 4; ++i) xa[i] = *(const float4*)(xg + i * 32);
#pragma unroll
    for (int i = 0; i < 4; ++i) {
        float4 t = xa[i]; half4v hv;
        hv[0]=(_Float16)t.x; hv[1]=(_Float16)t.y; hv[2]=(_Float16)t.z; hv[3]=(_Float16)t.w;
        *(half4v*)(&xs[0][srow * 136 + sg * 4 + i * 32]) = hv;
    }
#pragma unroll
    for (int i = 0; i < 4; ++i) xa[i] = *(const float4*)(xg + 128 + i * 32);
#pragma unroll
    for (int nf = 0; nf < 3; ++nf) wf[0][nf] = *(const half8*)(wgb + nf * 16384);
    __syncthreads();

    int cur = 0;
    for (int kt = 0; kt < 8; ++kt) {
        if (kt < 7) {
#pragma unroll
            for (int i = 0; i < 4; ++i) {
                float4 t = xa[i]; half4v hv;
                hv[0]=(_Float16)t.x; hv[1]=(_Float16)t.y; hv[2]=(_Float16)t.z; hv[3]=(_Float16)t.w;
                *(half4v*)(&xs[cur ^ 1][srow * 136 + sg * 4 + i * 32]) = hv;
            }
            if (kt < 6) {
#pragma unroll
                for (int i = 0; i < 4; ++i)
                    xa[i] = *(const float4*)(xg + (kt + 2) * 128 + i * 32);
            }
        }
#pragma unroll
        for (int s = 0; s < 4; ++s) {
            const int ss = kt * 4 + s;
            const int csw = ss & 1;
            if (ss + 1 < 32) {
#pragma unroll
                for (int nf = 0; nf < 3; ++nf)
                    wf[csw ^ 1][nf] = *(const half8*)(wgb + nf * 16384 + (ss + 1) * 32);
            }
            half8 af[2];
#pragma unroll
            for (int mf = 0; mf < 2; ++mf)
                af[mf] = *(const half8*)(&xs[cur][(mf * 16 + fr) * 136 + s * 32 + fq * 8]);
#pragma unroll
            for (int mf = 0; mf < 2; ++mf)
#pragma unroll
                for (int nf = 0; nf < 3; ++nf)
                    acc[mf][nf] = MFMA_F16(af[mf], wf[csw][nf], acc[mf][nf], 0, 0, 0);
        }
        __syncthreads();
        cur ^= 1;
    }

#pragma unroll
    for (int nf = 0; nf < 3; ++nf) {
        int n0 = c0 + nf * 16 + fr;
#pragma unroll
        for (int mf = 0; mf < 2; ++mf) {
            int mb = row0 + mf * 16 + fq * 4;
            if (n0 < 128) {
#pragma unroll
                for (int r = 0; r < 4; ++r) qh[(mb + r) * 128 + n0] = (_Float16)acc[mf][nf][r];
            } else if (n0 < 256) {
#pragma unroll
                for (int r = 0; r < 4; ++r) kh[(mb + r) * 128 + (n0 - 128)] = (_Float16)acc[mf][nf][r];
            } else {
                half4v pv;
#pragma unroll
                for (int r = 0; r < 4; ++r) pv[r] = (_Float16)acc[mf][nf][r];
                *(half4v*)(&vth[((mb >> 11) * 128 + (n0 - 256)) * 2048 + (mb & 2047)]) = pv;
            }
        }
    }
}

// ---------------- kernel 2: causal flash attention, split-KV (chunk = 4 kv-tiles) ----------------
// 1152 blocks x 256 threads (4 waves). bid = u*8 + b (batch pinned per XCD).
// nc(qt) = (qt>>2)+1. LDS exactly 40 KB (XOR-swizzled, no pads) -> 4 blocks/CU.
__global__ __launch_bounds__(256, 4) void attn_k(const _Float16* __restrict__ qh,
                                                 const _Float16* __restrict__ kh,
                                                 const _Float16* __restrict__ vth,
                                                 _Float16* __restrict__ part,
                                                 float* __restrict__ stats,
                                                 float* __restrict__ out) {
    __shared__ _Float16 ks[64 * 128];   // K tile, XOR-swizzled rows
    __shared__ _Float16 vs[128 * 64];   // Vt tile, XOR-swizzled rows
    __shared__ _Float16 ps[64 * 64];    // P, XOR-swizzled rows (per-wave 16-row slices)
    char* ksb = (char*)ks;
    char* vsb = (char*)vs;
    char* psb = (char*)ps;

    int bid = blockIdx.x;
    int b = bid & 7;
    int u = bid >> 3;
    int qt, c;
    if (u < 4)        { qt = u;                     c = 0; }
    else if (u < 12)  { qt = 4  + ((u - 4) >> 1);   c = (u - 4) & 1; }
    else if (u < 24)  { qt = 8  + (u - 12) / 3;     c = (u - 12) % 3; }
    else if (u < 40)  { qt = 12 + ((u - 24) >> 2);  c = (u - 24) & 3; }
    else if (u < 60)  { qt = 16 + (u - 40) / 5;     c = (u - 40) % 5; }
    else if (u < 84)  { qt = 20 + (u - 60) / 6;     c = (u - 60) % 6; }
    else if (u < 112) { qt = 24 + (u - 84) / 7;     c = (u - 84) % 7; }
    else              { qt = 28 + ((u - 112) >> 3); c = (u - 112) & 7; }
    int j0 = c * 4;
    int j1 = j0 + 4 < qt + 1 ? j0 + 4 : qt + 1;

    int tid = threadIdx.x, w = tid >> 6, l = tid & 63;
    int fr = l & 15, fq = l >> 4;
    int xw = (fr & 7) << 4;   // XOR key for rows this lane reads (row%8 == fr%8)

    half8 qf[4];
    const _Float16* qp = qh + ((b * 2048 + qt * 64 + w * 16 + fr) << 7);
#pragma unroll
    for (int cc = 0; cc < 4; ++cc) qf[cc] = *(const half8*)(qp + cc * 32 + fq * 8);

    uint4 kreg[4], vreg[4];
#define LOAD_TILE(j) do {                                                                 \
    _Pragma("unroll")                                                                     \
    for (int uu = 0; uu < 4; ++uu) {                                                      \
        int ci = tid + uu * 256;                                                          \
        kreg[uu] = *(const uint4*)(kh + (((b << 11) + ((j) << 6) + (ci >> 4)) << 7) + (ci & 15) * 8); \
        vreg[uu] = *(const uint4*)(vth + ((((b << 7) + (ci >> 3)) << 11) + ((j) << 6) + (ci & 7) * 8)); \
    } } while (0)
#define WRITE_TILE() do {                                                                 \
    _Pragma("unroll")                                                                     \
    for (int uu = 0; uu < 4; ++uu) {                                                      \
        int ci = tid + uu * 256;                                                          \
        int kr = ci >> 4;                                                                 \
        *(uint4*)(ksb + kr * 256 + (((ci & 15) * 16) ^ ((kr & 7) << 4))) = kreg[uu];      \
        int vd = ci >> 3;                                                                 \
        *(uint4*)(vsb + vd * 128 + (((ci & 7) * 16) ^ ((vd & 7) << 4))) = vreg[uu];       \
    } } while (0)

    f32x4 acc[8] = {};
    float mrow[4], lrow[4];
#pragma unroll
    for (int r = 0; r < 4; ++r) { mrow[r] = -1e30f; lrow[r] = 0.0f; }

    LOAD_TILE(j0);
    WRITE_TILE();
    if (j0 + 1 < j1) LOAD_TILE(j0 + 1);
    __syncthreads();

    for (int j = j0; j < j1; ++j) {
        // ---- S = Q K^T; D: col = fr (kv), row = fq*4+r (q) ----
        f32x4 s[4] = {};
#pragma unroll
        for (int n = 0; n < 4; ++n) {
            const char* krow = ksb + (n * 16 + fr) * 256;
#pragma unroll
            for (int cc = 0; cc < 4; ++cc) {
                half8 kf = *(const half8*)(krow + ((cc * 64 + fq * 16) ^ xw));
                s[n] = MFMA_F16(qf[cc], kf, s[n], 0, 0, 0);
            }
        }
        const float sc = 0.088388347648318447f;  // 1/sqrt(128)
        if (j == qt) {
#pragma unroll
            for (int n = 0; n < 4; ++n)
#pragma unroll
                for (int r = 0; r < 4; ++r) {
                    int qrow = w * 16 + fq * 4 + r;
                    int kcol = n * 16 + fr;
                    float v = s[n][r] * sc;
                    s[n][r] = (kcol > qrow) ? -1e30f : v;
                }
        } else {
#pragma unroll
            for (int n = 0; n < 4; ++n)
#pragma unroll
                for (int r = 0; r < 4; ++r) s[n][r] *= sc;
        }

        // ---- online softmax (16-lane row groups) ----
        float mx[4];
#pragma unroll
        for (int r = 0; r < 4; ++r)
            mx[r] = fmaxf(fmaxf(s[0][r], s[1][r]), fmaxf(s[2][r], s[3][r]));
#pragma unroll
        for (int off = 1; off < 16; off <<= 1)
#pragma unroll
            for (int r = 0; r < 4; ++r) mx[r] = fmaxf(mx[r], __shfl_xor(mx[r], off));
        float al[4];
#pragma unroll
        for (int r = 0; r < 4; ++r) {
            float nm = fmaxf(mrow[r], mx[r]);
            al[r] = __expf(mrow[r] - nm);
            mrow[r] = nm;
        }
        float rs[4] = {0.f, 0.f, 0.f, 0.f};
#pragma unroll
        for (int n = 0; n < 4; ++n)
#pragma unroll
            for (int r = 0; r < 4; ++r) {
                float p = __expf(s[n][r] - mrow[r]);
                s[n][r] = p;
                rs[r] += p;
            }
#pragma unroll
        for (int off = 1; off < 16; off <<= 1)
#pragma unroll
            for (int r = 0; r < 4; ++r) rs[r] += __shfl_xor(rs[r], off);
#pragma unroll
        for (int r = 0; r < 4; ++r) lrow[r] = lrow[r] * al[r] + rs[r];
#pragma unroll
        for (int dt = 0; dt < 8; ++dt)
#pragma unroll
            for (int r = 0; r < 4; ++r) acc[dt][r] *= al[r];

        // ---- P -> per-wave LDS slice (swizzled), then PV ----
#pragma unroll
        for (int n = 0; n < 4; ++n)
#pragma unroll
            for (int r = 0; r < 4; ++r) {
                int q = w * 16 + fq * 4 + r;
                *(_Float16*)(psb + q * 128 + ((2 * (n * 16 + fr)) ^ ((q & 7) << 4))) =
                    (_Float16)s[n][r];
            }

        half8 pa[2];
        {
            const char* prow = psb + (w * 16 + fr) * 128;
#pragma unroll
            for (int c2 = 0; c2 < 2; ++c2)
                pa[c2] = *(const half8*)(prow + ((c2 * 64 + fq * 16) ^ xw));
        }
#pragma unroll
        for (int dt = 0; dt < 8; ++dt) {
            const char* vrow = vsb + (dt * 16 + fr) * 128;
#pragma unroll
            for (int c2 = 0; c2 < 2; ++c2) {
                half8 vf = *(const half8*)(vrow + ((c2 * 64 + fq * 16) ^ xw));
                acc[dt] = MFMA_F16(pa[c2], vf, acc[dt], 0, 0, 0);
            }
        }

        if (j + 1 < j1) {
            __syncthreads();
            WRITE_TILE();
            if (j + 2 < j1) LOAD_TILE(j + 2);
            __syncthreads();
        }
    }

    float inv[4];
#pragma unroll
    for (int r = 0; r < 4; ++r) inv[r] = 1.0f / lrow[r];

    if (qt < 4) {
        // single chunk: final f32 output directly
        float* op = out + ((b * 2048 + qt * 64 + w * 16 + fq * 4) << 7) + fr;
#pragma unroll
        for (int dt = 0; dt < 8; ++dt)
#pragma unroll
            for (int r = 0; r < 4; ++r)
                op[r * 128 + dt * 16] = acc[dt][r] * inv[r];
    } else {
        // lane-contiguous partial: part[bid][w][dt][r][fq][fr]
        _Float16* op = part + bid * 8192 + w * 2048 + fq * 16 + fr;
#pragma unroll
        for (int dt = 0; dt < 8; ++dt)
#pragma unroll
            for (int r = 0; r < 4; ++r)
                op[dt * 256 + r * 64] = (_Float16)(acc[dt][r] * inv[r]);
        if (fr == 0) {
#pragma unroll
            for (int r = 0; r < 4; ++r) {
                int ridx = bid * 64 + w * 16 + fq * 4 + r;
                stats[ridx * 2]     = mrow[r];
                stats[ridx * 2 + 1] = lrow[r];
            }
        }
    }
#undef LOAD_TILE
#undef WRITE_TILE
}

// ---------------- kernel 3: combine split-KV partials (qt >= 4) ----------------
// 224 blocks (b, qt in [4,32)) x 256 threads.
__global__ __launch_bounds__(256) void comb_k(const _Float16* __restrict__ part,
                                              const float* __restrict__ stats,
                                              float* __restrict__ out) {
    int bid = blockIdx.x;
    int b = bid & 7, qt = 4 + (bid >> 3);
    int nc = (qt >> 2) + 1;
    int u0;
    if      (qt < 8)  u0 = 4   + 2 * (qt - 4);
    else if (qt < 12) u0 = 12  + 3 * (qt - 8);
    else if (qt < 16) u0 = 24  + 4 * (qt - 12);
    else if (qt < 20) u0 = 40  + 5 * (qt - 16);
    else if (qt < 24) u0 = 60  + 6 * (qt - 20);
    else if (qt < 28) u0 = 84  + 7 * (qt - 24);
    else              u0 = 112 + 8 * (qt - 28);

    int t = threadIdx.x;
    int row = t >> 2, g = t & 3;
    int w = row >> 4, fq = (row >> 2) & 3, r = row & 3;

    float mstar = -1e30f, mv[8], lv[8];
#pragma unroll
    for (int cc = 0; cc < 8; ++cc) {
        if (cc < nc) {
            int sidx = (((u0 + cc) << 3) + b) * 64 + row;
            mv[cc] = stats[sidx * 2];
            lv[cc] = stats[sidx * 2 + 1];
            mstar = fmaxf(mstar, mv[cc]);
        }
    }
    float den = 0.f, wc[8];
#pragma unroll
    for (int cc = 0; cc < 8; ++cc) {
        if (cc < nc) { wc[cc] = __expf(mv[cc] - mstar) * lv[cc]; den += wc[cc]; }
        else wc[cc] = 0.f;
    }
    float a[32] = {};
#pragma unroll
    for (int cc = 0; cc < 8; ++cc) {
        if (cc < nc) {
            const _Float16* pp = part + ((((u0 + cc) << 3) + b) * 8192)
                                 + w * 2048 + r * 64 + fq * 16;
            float wcc = wc[cc];
#pragma unroll
            for (int dd = 0; dd < 2; ++dd) {
                half8 h0 = *(const half8*)(pp + (2 * g + dd) * 256);
                half8 h1 = *(const half8*)(pp + (2 * g + dd) * 256 + 8);
#pragma unroll
                for (int e = 0; e < 8; ++e) {
                    a[dd * 16 + e]     += wcc * (float)h0[e];
                    a[dd * 16 + 8 + e] += wcc * (float)h1[e];
                }
            }
        }
    }
    float id = 1.0f / den;
    float* op = out + (b * 2048 + qt * 64 + row) * 128 + g * 32;
#pragma unroll
    for (int uu = 0; uu < 8; ++uu) {
        float4 o;
        o.x = a[uu * 4]     * id;
        o.y = a[uu * 4 + 1] * id;
        o.z = a[uu * 4 + 2] * id;
        o.w = a[uu * 4 + 3] * id;
        *(float4*)(op + uu * 4) = o;
    }
}

extern "C" void kernel_launch(void* const* d_in, const int* in_sizes, int n_in,
                              void* d_out, int out_size, void* d_ws, size_t ws_size,
                              hipStream_t stream) {
    const float* x  = (const float*)d_in[0];
    const float* wq = (const float*)d_in[1];
    const float* wk = (const float*)d_in[2];
    const float* wv = (const float*)d_in[3];

    char* ws = (char*)d_ws;
    _Float16* wh   = (_Float16*)(ws);                    // 768 KB
    _Float16* qhp  = (_Float16*)(ws + (1u  << 20));      // 4 MB
    _Float16* khp  = (_Float16*)(ws + (5u  << 20));      // 4 MB
    _Float16* vtp  = (_Float16*)(ws + (9u  << 20));      // 4 MB
    _Float16* part = (_Float16*)(ws + (13u << 20));      // 1152*16KB = 18.9 MB
    float*    stat = (float*)   (ws + (32u << 20));      // 590 KB

    wconv_k<<<192, 256, 0, stream>>>(wq, wk, wv, wh);
    qkv_k<<<1024, 256, 0, stream>>>(x, wh, qhp, khp, vtp);
    attn_k<<<1152, 256, 0, stream>>>(qhp, khp, vtp, part, stat, (float*)d_out);
    comb_k<<<224, 256, 0, stream>>>(part, stat, (float*)d_out);
}

// Round 9
// 131.533 us; speedup vs baseline: 1.0904x; 1.0882x over previous
//
#include <hip/hip_runtime.h>
#include <hip/hip_fp16.h>

typedef _Float16 half8  __attribute__((ext_vector_type(8)));
typedef _Float16 half4v __attribute__((ext_vector_type(4)));
typedef float    f32x4  __attribute__((ext_vector_type(4)));

#define MFMA_F16 __builtin_amdgcn_mfma_f32_16x16x32_f16

__device__ __forceinline__ unsigned pack_f16(float a, float b) {
    union { __fp16 h __attribute__((ext_vector_type(2))); unsigned u; } cv;
    cv.h = __builtin_amdgcn_cvt_pkrtz(a, b);
    return cv.u;
}

// ---------------- kernel 0: W_q|W_k|W_v f32 -> concat f16 [384][1024] ----------------
__global__ __launch_bounds__(256) void wconv_k(const float* __restrict__ wq,
                                               const float* __restrict__ wk,
                                               const float* __restrict__ wv,
                                               _Float16* __restrict__ wh) {
    int i = (blockIdx.x * 256 + threadIdx.x) * 8;
    const float* src; int off;
    if (i < 131072)      { src = wq; off = i; }
    else if (i < 262144) { src = wk; off = i - 131072; }
    else                 { src = wv; off = i - 262144; }
    float4 a = *(const float4*)(src + off);
    float4 b = *(const float4*)(src + off + 4);
    half8 h;
    h[0]=(_Float16)a.x; h[1]=(_Float16)a.y; h[2]=(_Float16)a.z; h[3]=(_Float16)a.w;
    h[4]=(_Float16)b.x; h[5]=(_Float16)b.y; h[6]=(_Float16)b.z; h[7]=(_Float16)b.w;
    *(half8*)(wh + i) = h;
}

// ---------------- kernel 1: fused QKV projection ----------------
// V tokens stored with per-64 slot permutation: bit-swap (b5 b4 b3 b2 -> b5 b3 b2 b4),
// so attention's PV A-fragment is a contiguous 16B LDS read in permuted-kv order.
__global__ __launch_bounds__(256, 4) void qkv_k(const float* __restrict__ x,
                                                const _Float16* __restrict__ wh,
                                                _Float16* __restrict__ qh,
                                                _Float16* __restrict__ kh,
                                                _Float16* __restrict__ vth) {
    __shared__ _Float16 xs[2][32 * 136];
    const int tid = threadIdx.x;
    const int w = tid >> 6, l = tid & 63;
    const int fr = l & 15, fq = l >> 4;
    const int rb = blockIdx.x >> 1, cb = blockIdx.x & 1;
    const int row0 = rb * 32;
    const int c0 = cb * 192 + w * 48;

    const int srow = tid >> 3, sg = tid & 7;
    const float* xg = x + (row0 + srow) * 1024 + sg * 4;
    const _Float16* wgb = wh + (c0 + fr) * 1024 + fq * 8;

    f32x4 acc[2][3] = {};
    float4 xa[4];
    half8 wf[2][3];

#pragma unroll
    for (int i = 0; i < 4; ++i) xa[i] = *(const float4*)(xg + i * 32);
#pragma unroll
    for (int i = 0; i < 4; ++i) {
        float4 t = xa[i]; half4v hv;
        hv[0]=(_Float16)t.x; hv[1]=(_Float16)t.y; hv[2]=(_Float16)t.z; hv[3]=(_Float16)t.w;
        *(half4v*)(&xs[0][srow * 136 + sg * 4 + i * 32]) = hv;
    }
#pragma unroll
    for (int i = 0; i < 4; ++i) xa[i] = *(const float4*)(xg + 128 + i * 32);
#pragma unroll
    for (int nf = 0; nf < 3; ++nf) wf[0][nf] = *(const half8*)(wgb + nf * 16384);
    __syncthreads();

    int cur = 0;
    for (int kt = 0; kt < 8; ++kt) {
        if (kt < 7) {
#pragma unroll
            for (int i = 0; i < 4; ++i) {
                float4 t = xa[i]; half4v hv;
                hv[0]=(_Float16)t.x; hv[1]=(_Float16)t.y; hv[2]=(_Float16)t.z; hv[3]=(_Float16)t.w;
                *(half4v*)(&xs[cur ^ 1][srow * 136 + sg * 4 + i * 32]) = hv;
            }
            if (kt < 6) {
#pragma unroll
                for (int i = 0; i < 4; ++i)
                    xa[i] = *(const float4*)(xg + (kt + 2) * 128 + i * 32);
            }
        }
#pragma unroll
        for (int s = 0; s < 4; ++s) {
            const int ss = kt * 4 + s;
            const int csw = ss & 1;
            if (ss + 1 < 32) {
#pragma unroll
                for (int nf = 0; nf < 3; ++nf)
                    wf[csw ^ 1][nf] = *(const half8*)(wgb + nf * 16384 + (ss + 1) * 32);
            }
            half8 af[2];
#pragma unroll
            for (int mf = 0; mf < 2; ++mf)
                af[mf] = *(const half8*)(&xs[cur][(mf * 16 + fr) * 136 + s * 32 + fq * 8]);
#pragma unroll
            for (int mf = 0; mf < 2; ++mf)
#pragma unroll
                for (int nf = 0; nf < 3; ++nf)
                    acc[mf][nf] = MFMA_F16(af[mf], wf[csw][nf], acc[mf][nf], 0, 0, 0);
        }
        __syncthreads();
        cur ^= 1;
    }

#pragma unroll
    for (int nf = 0; nf < 3; ++nf) {
        int n0 = c0 + nf * 16 + fr;
#pragma unroll
        for (int mf = 0; mf < 2; ++mf) {
            int mb = row0 + mf * 16 + fq * 4;
            if (n0 < 128) {
#pragma unroll
                for (int r = 0; r < 4; ++r) qh[(mb + r) * 128 + n0] = (_Float16)acc[mf][nf][r];
            } else if (n0 < 256) {
#pragma unroll
                for (int r = 0; r < 4; ++r) kh[(mb + r) * 128 + (n0 - 128)] = (_Float16)acc[mf][nf][r];
            } else {
                half4v pv;
#pragma unroll
                for (int r = 0; r < 4; ++r) pv[r] = (_Float16)acc[mf][nf][r];
                int t = mb & 2047;
                int tl = t & 63;
                int tp = (t & ~63) | (tl & 35) | ((tl & 12) << 1) | ((tl & 16) >> 2);
                *(half4v*)(&vth[((mb >> 11) * 128 + (n0 - 256)) * 2048 + tp]) = pv;
            }
        }
    }
}

// ---------------- kernel 2: causal flash attention, swapped-QK, shuffle-free PV ----------------
// 640 blocks x 256 threads (4 waves), chunk = 8 kv-tiles. b = bid&7 (batch pinned per XCD).
// S^T = mfma(K,Q): lane q = fr, kv = n*16 + fq*4 + r; per-lane softmax stats (2 shfl).
// PV uses permuted-kv order (baked into vth) so B-frag = lane's own packed P. O^T accum.
__global__ __launch_bounds__(256, 4) void attn_k(const _Float16* __restrict__ qh,
                                                 const _Float16* __restrict__ kh,
                                                 const _Float16* __restrict__ vth,
                                                 _Float16* __restrict__ part,
                                                 float* __restrict__ stats,
                                                 float* __restrict__ out) {
    __shared__ _Float16 ks[64 * 128];   // K tile, XOR-swizzled rows
    __shared__ _Float16 vs[128 * 64];   // Vt tile (slot order), XOR-swizzled rows
    char* ksb = (char*)ks;
    char* vsb = (char*)vs;

    int bid = blockIdx.x;
    int b = bid & 7;
    int u = bid >> 3;
    int qt, c;
    if (u < 8)       { qt = u;                  c = 0; }
    else if (u < 24) { qt = 8  + ((u - 8) >> 1);  c = (u - 8) & 1; }
    else if (u < 48) { qt = 16 + (u - 24) / 3;    c = (u - 24) % 3; }
    else             { qt = 24 + ((u - 48) >> 2); c = (u - 48) & 3; }
    int j0 = c * 8;
    int j1 = j0 + 8 < qt + 1 ? j0 + 8 : qt + 1;

    int tid = threadIdx.x, w = tid >> 6, l = tid & 63;
    int fr = l & 15, fq = l >> 4;
    int xw = (fr & 7) << 4;

    half8 qf[4];
    const _Float16* qp = qh + ((b * 2048 + qt * 64 + w * 16 + fr) << 7);
#pragma unroll
    for (int cc = 0; cc < 4; ++cc) qf[cc] = *(const half8*)(qp + cc * 32 + fq * 8);

    uint4 kreg[4], vreg[4];
#define LOAD_TILE(j) do {                                                                 \
    _Pragma("unroll")                                                                     \
    for (int uu = 0; uu < 4; ++uu) {                                                      \
        int ci = tid + uu * 256;                                                          \
        kreg[uu] = *(const uint4*)(kh + (((b << 11) + ((j) << 6) + (ci >> 4)) << 7) + (ci & 15) * 8); \
        vreg[uu] = *(const uint4*)(vth + ((((b << 7) + (ci >> 3)) << 11) + ((j) << 6) + (ci & 7) * 8)); \
    } } while (0)
#define WRITE_TILE() do {                                                                 \
    _Pragma("unroll")                                                                     \
    for (int uu = 0; uu < 4; ++uu) {                                                      \
        int ci = tid + uu * 256;                                                          \
        int kr = ci >> 4;                                                                 \
        *(uint4*)(ksb + kr * 256 + (((ci & 15) * 16) ^ ((kr & 7) << 4))) = kreg[uu];      \
        int vd = ci >> 3;                                                                 \
        *(uint4*)(vsb + vd * 128 + (((ci & 7) * 16) ^ ((vd & 7) << 4))) = vreg[uu];       \
    } } while (0)

    f32x4 acc[8] = {};                 // O^T: lane q = w*16+fr; d = dt*16 + fq*4 + r
    float mrow = -1e30f, lrow = 0.0f;  // per-lane (q) scalars

    LOAD_TILE(j0);
    WRITE_TILE();
    if (j0 + 1 < j1) LOAD_TILE(j0 + 1);
    __syncthreads();

    for (int j = j0; j < j1; ++j) {
        // ---- S^T = K Q^T: lane holds q = fr, kv = n*16 + fq*4 + r ----
        f32x4 s[4] = {};
#pragma unroll
        for (int n = 0; n < 4; ++n) {
            const char* krow = ksb + (n * 16 + fr) * 256;
#pragma unroll
            for (int cc = 0; cc < 4; ++cc) {
                half8 kf = *(const half8*)(krow + ((cc * 64 + fq * 16) ^ xw));
                s[n] = MFMA_F16(kf, qf[cc], s[n], 0, 0, 0);
            }
        }
        const float sc = 0.088388347648318447f;  // 1/sqrt(128)
        if (j == qt) {
            int qrow = w * 16 + fr;
#pragma unroll
            for (int n = 0; n < 4; ++n)
#pragma unroll
                for (int r = 0; r < 4; ++r) {
                    int kcol = n * 16 + fq * 4 + r;
                    float v = s[n][r] * sc;
                    s[n][r] = (kcol > qrow) ? -1e30f : v;
                }
        } else {
#pragma unroll
            for (int n = 0; n < 4; ++n)
#pragma unroll
                for (int r = 0; r < 4; ++r) s[n][r] *= sc;
        }

        // ---- online softmax: per-lane row stats, 2 shfl total ----
        float mx = s[0][0];
#pragma unroll
        for (int n = 0; n < 4; ++n)
#pragma unroll
            for (int r = 0; r < 4; ++r) mx = fmaxf(mx, s[n][r]);
        mx = fmaxf(mx, __shfl_xor(mx, 16));
        mx = fmaxf(mx, __shfl_xor(mx, 32));
        float nm = fmaxf(mrow, mx);
        float al = __expf(mrow - nm);
        mrow = nm;
        float rs = 0.f;
#pragma unroll
        for (int n = 0; n < 4; ++n)
#pragma unroll
            for (int r = 0; r < 4; ++r) {
                float p = __expf(s[n][r] - mrow);
                s[n][r] = p;
                rs += p;
            }
        rs += __shfl_xor(rs, 16);
        rs += __shfl_xor(rs, 32);
        lrow = lrow * al + rs;
#pragma unroll
        for (int dt = 0; dt < 8; ++dt)
#pragma unroll
            for (int r = 0; r < 4; ++r) acc[dt][r] *= al;

        // ---- P -> f16, in-register; B-frag is the lane's OWN values (permuted kv) ----
        unsigned pk01[4], pk23[4];
#pragma unroll
        for (int n = 0; n < 4; ++n) {
            pk01[n] = pack_f16(s[n][0], s[n][1]);
            pk23[n] = pack_f16(s[n][2], s[n][3]);
        }

#pragma unroll
        for (int j2 = 0; j2 < 2; ++j2) {
            union { unsigned u[4]; half8 h; } pb;
            pb.u[0] = pk01[2 * j2];     pb.u[1] = pk23[2 * j2];
            pb.u[2] = pk01[2 * j2 + 1]; pb.u[3] = pk23[2 * j2 + 1];
#pragma unroll
            for (int dt = 0; dt < 8; ++dt) {
                const char* vrow = vsb + (dt * 16 + fr) * 128;
                half8 vf = *(const half8*)(vrow + ((j2 * 64 + fq * 16) ^ xw));
                acc[dt] = MFMA_F16(vf, pb.h, acc[dt], 0, 0, 0);
            }
        }

        if (j + 1 < j1) {
            __syncthreads();
            WRITE_TILE();
            if (j + 2 < j1) LOAD_TILE(j + 2);
            __syncthreads();
        }
    }

    float inv = 1.0f / lrow;

    if (qt < 8) {
        // single chunk: O^T -> out directly; per dt a float4 (d = dt*16 + fq*4 ..)
        float* op = out + ((b * 2048 + qt * 64 + w * 16 + fr) << 7) + fq * 4;
#pragma unroll
        for (int dt = 0; dt < 8; ++dt) {
            float4 o;
            o.x = acc[dt][0] * inv; o.y = acc[dt][1] * inv;
            o.z = acc[dt][2] * inv; o.w = acc[dt][3] * inv;
            *(float4*)(op + dt * 16) = o;
        }
    } else {
        // partial: part[bid][w][dt][l][r] (8B per lane per dt, contiguous per store)
        _Float16* op = part + bid * 8192 + w * 2048 + l * 4;
#pragma unroll
        for (int dt = 0; dt < 8; ++dt) {
            half4v h;
#pragma unroll
            for (int r = 0; r < 4; ++r) h[r] = (_Float16)(acc[dt][r] * inv);
            *(half4v*)(op + dt * 256) = h;
        }
        if (l < 16) {
            int ridx = bid * 64 + w * 16 + l;
            float2 st; st.x = mrow; st.y = lrow;
            *(float2*)(&stats[ridx * 2]) = st;
        }
    }
#undef LOAD_TILE
#undef WRITE_TILE
}

// ---------------- kernel 3: combine split-KV partials (qt >= 8) ----------------
__global__ __launch_bounds__(256) void comb_k(const _Float16* __restrict__ part,
                                              const float* __restrict__ stats,
                                              float* __restrict__ out) {
    int bid = blockIdx.x;
    int b = bid & 7, qt = 8 + (bid >> 3);
    int u0 = qt < 16 ? 8 + 2 * (qt - 8) : qt < 24 ? 24 + 3 * (qt - 16) : 48 + 4 * (qt - 24);
    int nc = qt < 16 ? 2 : qt < 24 ? 3 : 4;
    int t = threadIdx.x;
    int row = t >> 2, g = t & 3;
    int w = row >> 4, q16 = row & 15;

    float mstar = -1e30f, mv[4], lv[4];
#pragma unroll
    for (int cc = 0; cc < 4; ++cc) {
        if (cc < nc) {
            int sidx = (((u0 + cc) << 3) + b) * 64 + row;
            mv[cc] = stats[sidx * 2];
            lv[cc] = stats[sidx * 2 + 1];
            mstar = fmaxf(mstar, mv[cc]);
        }
    }
    float den = 0.f, wc[4];
#pragma unroll
    for (int cc = 0; cc < 4; ++cc) {
        if (cc < nc) { wc[cc] = __expf(mv[cc] - mstar) * lv[cc]; den += wc[cc]; }
        else wc[cc] = 0.f;
    }
    // a[dd*16 + fq*4 + r] for dt = 2g+dd
    float a[32] = {};
#pragma unroll
    for (int cc = 0; cc < 4; ++cc) {
        if (cc < nc) {
            const _Float16* pp = part + ((((u0 + cc) << 3) + b) * 8192) + w * 2048;
            float wcc = wc[cc];
#pragma unroll
            for (int dd = 0; dd < 2; ++dd) {
                int dt = 2 * g + dd;
#pragma unroll
                for (int fq = 0; fq < 4; ++fq) {
                    half4v h = *(const half4v*)(pp + dt * 256 + (fq * 16 + q16) * 4);
#pragma unroll
                    for (int r = 0; r < 4; ++r)
                        a[dd * 16 + fq * 4 + r] += wcc * (float)h[r];
                }
            }
        }
    }
    float id = 1.0f / den;
    float* op = out + (b * 2048 + qt * 64 + row) * 128 + g * 32;
#pragma unroll
    for (int uu = 0; uu < 8; ++uu) {
        float4 o;
        o.x = a[uu * 4]     * id;
        o.y = a[uu * 4 + 1] * id;
        o.z = a[uu * 4 + 2] * id;
        o.w = a[uu * 4 + 3] * id;
        *(float4*)(op + uu * 4) = o;
    }
}

extern "C" void kernel_launch(void* const* d_in, const int* in_sizes, int n_in,
                              void* d_out, int out_size, void* d_ws, size_t ws_size,
                              hipStream_t stream) {
    const float* x  = (const float*)d_in[0];
    const float* wq = (const float*)d_in[1];
    const float* wk = (const float*)d_in[2];
    const float* wv = (const float*)d_in[3];

    char* ws = (char*)d_ws;
    _Float16* wh   = (_Float16*)(ws);                    // 768 KB
    _Float16* qhp  = (_Float16*)(ws + (1u  << 20));      // 4 MB
    _Float16* khp  = (_Float16*)(ws + (5u  << 20));      // 4 MB
    _Float16* vtp  = (_Float16*)(ws + (9u  << 20));      // 4 MB
    _Float16* part = (_Float16*)(ws + (13u << 20));      // 640*16KB = 10.5 MB
    float*    stat = (float*)   (ws + (24u << 20));      // 328 KB

    wconv_k<<<192, 256, 0, stream>>>(wq, wk, wv, wh);
    qkv_k<<<1024, 256, 0, stream>>>(x, wh, qhp, khp, vtp);
    attn_k<<<640, 256, 0, stream>>>(qhp, khp, vtp, part, stat, (float*)d_out);
    comb_k<<<192, 256, 0, stream>>>(part, stat, (float*)d_out);
}

// Round 10
// 107.574 us; speedup vs baseline: 1.3333x; 1.2227x over previous
//
#include <hip/hip_runtime.h>
#include <hip/hip_fp16.h>

typedef _Float16 half8  __attribute__((ext_vector_type(8)));
typedef _Float16 half4v __attribute__((ext_vector_type(4)));
typedef float    f32x4  __attribute__((ext_vector_type(4)));

#define MFMA_F16 __builtin_amdgcn_mfma_f32_16x16x32_f16

__device__ __forceinline__ unsigned pack_f16(float a, float b) {
    union { __fp16 h __attribute__((ext_vector_type(2))); unsigned u; } cv;
    cv.h = __builtin_amdgcn_cvt_pkrtz(a, b);
    return cv.u;
}

// ---------------- kernel 0: W_q|W_k|W_v f32 -> concat f16 [384][1024] ----------------
__global__ __launch_bounds__(256) void wconv_k(const float* __restrict__ wq,
                                               const float* __restrict__ wk,
                                               const float* __restrict__ wv,
                                               _Float16* __restrict__ wh) {
    int i = (blockIdx.x * 256 + threadIdx.x) * 8;
    const float* src; int off;
    if (i < 131072)      { src = wq; off = i; }
    else if (i < 262144) { src = wk; off = i - 131072; }
    else                 { src = wv; off = i - 262144; }
    float4 a = *(const float4*)(src + off);
    float4 b = *(const float4*)(src + off + 4);
    half8 h;
    h[0]=(_Float16)a.x; h[1]=(_Float16)a.y; h[2]=(_Float16)a.z; h[3]=(_Float16)a.w;
    h[4]=(_Float16)b.x; h[5]=(_Float16)b.y; h[6]=(_Float16)b.z; h[7]=(_Float16)b.w;
    *(half8*)(wh + i) = h;
}

// ---------------- kernel 1: fused QKV projection (R3/R4 proven config + V-permute) ----------------
// grid 512: rb=bid>>1 (64-row group), cb=bid&1 (192-col half). 256 thr = 4 waves.
// Wave w: 64 rows x 48 cols. K-step 128 (8 barriers total), dbuf LDS, reg prefetch.
__global__ __launch_bounds__(256, 2) void qkv_k(const float* __restrict__ x,
                                                const _Float16* __restrict__ wh,
                                                _Float16* __restrict__ qh,
                                                _Float16* __restrict__ kh,
                                                _Float16* __restrict__ vth) {
    __shared__ _Float16 xs[2][64 * 136];
    const int tid = threadIdx.x;
    const int w = tid >> 6, l = tid & 63;
    const int fr = l & 15, fq = l >> 4;
    const int rb = blockIdx.x >> 1, cb = blockIdx.x & 1;
    const int row0 = rb * 64;
    const int c0 = cb * 192 + w * 48;

    const int srow = tid >> 2, sg = tid & 3;
    const float* xg = x + (row0 + srow) * 1024 + sg * 4;
    const _Float16* wgb = wh + (c0 + fr) * 1024 + fq * 8;

    f32x4 acc[4][3] = {};
    float4 xa[8];
    half8 wf[2][3];

#pragma unroll
    for (int i = 0; i < 8; ++i) xa[i] = *(const float4*)(xg + i * 16);
#pragma unroll
    for (int i = 0; i < 8; ++i) {
        float4 t = xa[i]; half4v hv;
        hv[0]=(_Float16)t.x; hv[1]=(_Float16)t.y; hv[2]=(_Float16)t.z; hv[3]=(_Float16)t.w;
        *(half4v*)(&xs[0][srow * 136 + sg * 4 + i * 16]) = hv;
    }
#pragma unroll
    for (int i = 0; i < 8; ++i) xa[i] = *(const float4*)(xg + 128 + i * 16);
#pragma unroll
    for (int nf = 0; nf < 3; ++nf) wf[0][nf] = *(const half8*)(wgb + nf * 16384);
    __syncthreads();

    int cur = 0;
    for (int kt = 0; kt < 8; ++kt) {
        if (kt < 7) {
#pragma unroll
            for (int i = 0; i < 8; ++i) {
                float4 t = xa[i]; half4v hv;
                hv[0]=(_Float16)t.x; hv[1]=(_Float16)t.y; hv[2]=(_Float16)t.z; hv[3]=(_Float16)t.w;
                *(half4v*)(&xs[cur ^ 1][srow * 136 + sg * 4 + i * 16]) = hv;
            }
            if (kt < 6) {
#pragma unroll
                for (int i = 0; i < 8; ++i)
                    xa[i] = *(const float4*)(xg + (kt + 2) * 128 + i * 16);
            }
        }
#pragma unroll
        for (int s = 0; s < 4; ++s) {
            const int ss = kt * 4 + s;
            const int csw = ss & 1;
            if (ss + 1 < 32) {
#pragma unroll
                for (int nf = 0; nf < 3; ++nf)
                    wf[csw ^ 1][nf] = *(const half8*)(wgb + nf * 16384 + (ss + 1) * 32);
            }
            half8 af[4];
#pragma unroll
            for (int mf = 0; mf < 4; ++mf)
                af[mf] = *(const half8*)(&xs[cur][(mf * 16 + fr) * 136 + s * 32 + fq * 8]);
#pragma unroll
            for (int mf = 0; mf < 4; ++mf)
#pragma unroll
                for (int nf = 0; nf < 3; ++nf)
                    acc[mf][nf] = MFMA_F16(af[mf], wf[csw][nf], acc[mf][nf], 0, 0, 0);
        }
        __syncthreads();
        cur ^= 1;
    }

    // epilogue: row = row0 + mf*16 + fq*4 + r, col = c0 + nf*16 + fr
    // V stored with per-64-token slot permutation (bit-swap b4,b3,b2 -> rotated) so that
    // attention's PV B-fragment equals the lane's own packed P values.
#pragma unroll
    for (int nf = 0; nf < 3; ++nf) {
        int n0 = c0 + nf * 16 + fr;
#pragma unroll
        for (int mf = 0; mf < 4; ++mf) {
            int mb = row0 + mf * 16 + fq * 4;
            if (n0 < 128) {
#pragma unroll
                for (int r = 0; r < 4; ++r) qh[(mb + r) * 128 + n0] = (_Float16)acc[mf][nf][r];
            } else if (n0 < 256) {
#pragma unroll
                for (int r = 0; r < 4; ++r) kh[(mb + r) * 128 + (n0 - 128)] = (_Float16)acc[mf][nf][r];
            } else {
                half4v pv;
#pragma unroll
                for (int r = 0; r < 4; ++r) pv[r] = (_Float16)acc[mf][nf][r];
                int t = mb & 2047;
                int tl = t & 63;
                int tp = (t & ~63) | (tl & 35) | ((tl & 12) << 1) | ((tl & 16) >> 2);
                *(half4v*)(&vth[((mb >> 11) * 128 + (n0 - 256)) * 2048 + tp]) = pv;
            }
        }
    }
}

// ---------------- kernel 2: causal flash attention, swapped-QK, shuffle-free PV ----------------
// 640 blocks x 256 threads (4 waves), chunk = 8 kv-tiles. b = bid&7 (batch pinned per XCD).
// DOUBLE-BUFFERED K/V LDS, ONE barrier per iter: global loads for tile j+2 are issued
// before the compute phase, so the end-of-iter barrier's vmcnt drain finds them landed.
__global__ __launch_bounds__(256, 2) void attn_k(const _Float16* __restrict__ qh,
                                                 const _Float16* __restrict__ kh,
                                                 const _Float16* __restrict__ vth,
                                                 _Float16* __restrict__ part,
                                                 float* __restrict__ stats,
                                                 float* __restrict__ out) {
    __shared__ _Float16 ks[2][64 * 128];   // K tiles, XOR-swizzled rows
    __shared__ _Float16 vs[2][128 * 64];   // Vt tiles (slot order), XOR-swizzled rows

    int bid = blockIdx.x;
    int b = bid & 7;
    int u = bid >> 3;
    int qt, c;
    if (u < 8)       { qt = u;                  c = 0; }
    else if (u < 24) { qt = 8  + ((u - 8) >> 1);  c = (u - 8) & 1; }
    else if (u < 48) { qt = 16 + (u - 24) / 3;    c = (u - 24) % 3; }
    else             { qt = 24 + ((u - 48) >> 2); c = (u - 48) & 3; }
    int j0 = c * 8;
    int j1 = j0 + 8 < qt + 1 ? j0 + 8 : qt + 1;

    int tid = threadIdx.x, w = tid >> 6, l = tid & 63;
    int fr = l & 15, fq = l >> 4;
    int xw = (fr & 7) << 4;

    half8 qf[4];
    const _Float16* qp = qh + ((b * 2048 + qt * 64 + w * 16 + fr) << 7);
#pragma unroll
    for (int cc = 0; cc < 4; ++cc) qf[cc] = *(const half8*)(qp + cc * 32 + fq * 8);

    uint4 kreg[4], vreg[4];
#define LOAD_TILE(j) do {                                                                 \
    _Pragma("unroll")                                                                     \
    for (int uu = 0; uu < 4; ++uu) {                                                      \
        int ci = tid + uu * 256;                                                          \
        kreg[uu] = *(const uint4*)(kh + (((b << 11) + ((j) << 6) + (ci >> 4)) << 7) + (ci & 15) * 8); \
        vreg[uu] = *(const uint4*)(vth + ((((b << 7) + (ci >> 3)) << 11) + ((j) << 6) + (ci & 7) * 8)); \
    } } while (0)
#define WRITE_TILE(bb) do {                                                               \
    char* kd = (char*)(ks[bb]); char* vd2 = (char*)(vs[bb]);                              \
    _Pragma("unroll")                                                                     \
    for (int uu = 0; uu < 4; ++uu) {                                                      \
        int ci = tid + uu * 256;                                                          \
        int kr = ci >> 4;                                                                 \
        *(uint4*)(kd + kr * 256 + (((ci & 15) * 16) ^ ((kr & 7) << 4))) = kreg[uu];       \
        int vdd = ci >> 3;                                                                \
        *(uint4*)(vd2 + vdd * 128 + (((ci & 7) * 16) ^ ((vdd & 7) << 4))) = vreg[uu];     \
    } } while (0)

    f32x4 acc[8] = {};                 // O^T: lane q = w*16+fr; d = dt*16 + fq*4 + r
    float mrow = -1e30f, lrow = 0.0f;  // per-lane (q) scalars

    LOAD_TILE(j0);
    WRITE_TILE(0);
    if (j0 + 1 < j1) LOAD_TILE(j0 + 1);
    __syncthreads();

    int cur = 0;
    for (int j = j0; j < j1; ++j) {
        if (j + 1 < j1) {
            WRITE_TILE(cur ^ 1);                 // regs (tile j+1) -> other buffer
            if (j + 2 < j1) LOAD_TILE(j + 2);    // in flight across the compute phase
        }
        const char* ksb = (const char*)(ks[cur]);
        const char* vsb = (const char*)(vs[cur]);

        // ---- S^T = K Q^T: lane holds q = fr, kv = n*16 + fq*4 + r ----
        f32x4 s[4] = {};
#pragma unroll
        for (int n = 0; n < 4; ++n) {
            const char* krow = ksb + (n * 16 + fr) * 256;
#pragma unroll
            for (int cc = 0; cc < 4; ++cc) {
                half8 kf = *(const half8*)(krow + ((cc * 64 + fq * 16) ^ xw));
                s[n] = MFMA_F16(kf, qf[cc], s[n], 0, 0, 0);
            }
        }
        const float sc = 0.088388347648318447f;  // 1/sqrt(128)
        if (j == qt) {
            int qrow = w * 16 + fr;
#pragma unroll
            for (int n = 0; n < 4; ++n)
#pragma unroll
                for (int r = 0; r < 4; ++r) {
                    int kcol = n * 16 + fq * 4 + r;
                    float v = s[n][r] * sc;
                    s[n][r] = (kcol > qrow) ? -1e30f : v;
                }
        } else {
#pragma unroll
            for (int n = 0; n < 4; ++n)
#pragma unroll
                for (int r = 0; r < 4; ++r) s[n][r] *= sc;
        }

        // ---- online softmax: per-lane row stats, 2 shfl total ----
        float mx = s[0][0];
#pragma unroll
        for (int n = 0; n < 4; ++n)
#pragma unroll
            for (int r = 0; r < 4; ++r) mx = fmaxf(mx, s[n][r]);
        mx = fmaxf(mx, __shfl_xor(mx, 16));
        mx = fmaxf(mx, __shfl_xor(mx, 32));
        float nm = fmaxf(mrow, mx);
        float al = __expf(mrow - nm);
        mrow = nm;
        float rs = 0.f;
#pragma unroll
        for (int n = 0; n < 4; ++n)
#pragma unroll
            for (int r = 0; r < 4; ++r) {
                float p = __expf(s[n][r] - mrow);
                s[n][r] = p;
                rs += p;
            }
        rs += __shfl_xor(rs, 16);
        rs += __shfl_xor(rs, 32);
        lrow = lrow * al + rs;
#pragma unroll
        for (int dt = 0; dt < 8; ++dt)
#pragma unroll
            for (int r = 0; r < 4; ++r) acc[dt][r] *= al;

        // ---- P -> f16 in-register; B-frag is the lane's OWN values (permuted kv) ----
        unsigned pk01[4], pk23[4];
#pragma unroll
        for (int n = 0; n < 4; ++n) {
            pk01[n] = pack_f16(s[n][0], s[n][1]);
            pk23[n] = pack_f16(s[n][2], s[n][3]);
        }

#pragma unroll
        for (int j2 = 0; j2 < 2; ++j2) {
            union { unsigned u[4]; half8 h; } pb;
            pb.u[0] = pk01[2 * j2];     pb.u[1] = pk23[2 * j2];
            pb.u[2] = pk01[2 * j2 + 1]; pb.u[3] = pk23[2 * j2 + 1];
#pragma unroll
            for (int dt = 0; dt < 8; ++dt) {
                const char* vrow = vsb + (dt * 16 + fr) * 128;
                half8 vf = *(const half8*)(vrow + ((j2 * 64 + fq * 16) ^ xw));
                acc[dt] = MFMA_F16(vf, pb.h, acc[dt], 0, 0, 0);
            }
        }

        __syncthreads();
        cur ^= 1;
    }

    float inv = 1.0f / lrow;

    if (qt < 8) {
        // single chunk: O^T -> out directly; per dt a float4 (d = dt*16 + fq*4 ..)
        float* op = out + ((b * 2048 + qt * 64 + w * 16 + fr) << 7) + fq * 4;
#pragma unroll
        for (int dt = 0; dt < 8; ++dt) {
            float4 o;
            o.x = acc[dt][0] * inv; o.y = acc[dt][1] * inv;
            o.z = acc[dt][2] * inv; o.w = acc[dt][3] * inv;
            *(float4*)(op + dt * 16) = o;
        }
    } else {
        // partial: part[bid][w][dt][l][r] (8B per lane per dt, contiguous per store)
        _Float16* op = part + bid * 8192 + w * 2048 + l * 4;
#pragma unroll
        for (int dt = 0; dt < 8; ++dt) {
            half4v h;
#pragma unroll
            for (int r = 0; r < 4; ++r) h[r] = (_Float16)(acc[dt][r] * inv);
            *(half4v*)(op + dt * 256) = h;
        }
        if (l < 16) {
            int ridx = bid * 64 + w * 16 + l;
            float2 st; st.x = mrow; st.y = lrow;
            *(float2*)(&stats[ridx * 2]) = st;
        }
    }
#undef LOAD_TILE
#undef WRITE_TILE
}

// ---------------- kernel 3: combine split-KV partials (qt >= 8) ----------------
__global__ __launch_bounds__(256) void comb_k(const _Float16* __restrict__ part,
                                              const float* __restrict__ stats,
                                              float* __restrict__ out) {
    int bid = blockIdx.x;
    int b = bid & 7, qt = 8 + (bid >> 3);
    int u0 = qt < 16 ? 8 + 2 * (qt - 8) : qt < 24 ? 24 + 3 * (qt - 16) : 48 + 4 * (qt - 24);
    int nc = qt < 16 ? 2 : qt < 24 ? 3 : 4;
    int t = threadIdx.x;
    int row = t >> 2, g = t & 3;
    int w = row >> 4, q16 = row & 15;

    float mstar = -1e30f, mv[4], lv[4];
#pragma unroll
    for (int cc = 0; cc < 4; ++cc) {
        if (cc < nc) {
            int sidx = (((u0 + cc) << 3) + b) * 64 + row;
            mv[cc] = stats[sidx * 2];
            lv[cc] = stats[sidx * 2 + 1];
            mstar = fmaxf(mstar, mv[cc]);
        }
    }
    float den = 0.f, wc[4];
#pragma unroll
    for (int cc = 0; cc < 4; ++cc) {
        if (cc < nc) { wc[cc] = __expf(mv[cc] - mstar) * lv[cc]; den += wc[cc]; }
        else wc[cc] = 0.f;
    }
    // a[dd*16 + fq*4 + r] for dt = 2g+dd
    float a[32] = {};
#pragma unroll
    for (int cc = 0; cc < 4; ++cc) {
        if (cc < nc) {
            const _Float16* pp = part + ((((u0 + cc) << 3) + b) * 8192) + w * 2048;
            float wcc = wc[cc];
#pragma unroll
            for (int dd = 0; dd < 2; ++dd) {
                int dt = 2 * g + dd;
#pragma unroll
                for (int fq = 0; fq < 4; ++fq) {
                    half4v h = *(const half4v*)(pp + dt * 256 + (fq * 16 + q16) * 4);
#pragma unroll
                    for (int r = 0; r < 4; ++r)
                        a[dd * 16 + fq * 4 + r] += wcc * (float)h[r];
                }
            }
        }
    }
    float id = 1.0f / den;
    float* op = out + (b * 2048 + qt * 64 + row) * 128 + g * 32;
#pragma unroll
    for (int uu = 0; uu < 8; ++uu) {
        float4 o;
        o.x = a[uu * 4]     * id;
        o.y = a[uu * 4 + 1] * id;
        o.z = a[uu * 4 + 2] * id;
        o.w = a[uu * 4 + 3] * id;
        *(float4*)(op + uu * 4) = o;
    }
}

extern "C" void kernel_launch(void* const* d_in, const int* in_sizes, int n_in,
                              void* d_out, int out_size, void* d_ws, size_t ws_size,
                              hipStream_t stream) {
    const float* x  = (const float*)d_in[0];
    const float* wq = (const float*)d_in[1];
    const float* wk = (const float*)d_in[2];
    const float* wv = (const float*)d_in[3];

    char* ws = (char*)d_ws;
    _Float16* wh   = (_Float16*)(ws);                    // 768 KB
    _Float16* qhp  = (_Float16*)(ws + (1u  << 20));      // 4 MB
    _Float16* khp  = (_Float16*)(ws + (5u  << 20));      // 4 MB
    _Float16* vtp  = (_Float16*)(ws + (9u  << 20));      // 4 MB
    _Float16* part = (_Float16*)(ws + (13u << 20));      // 640*16KB = 10.5 MB
    float*    stat = (float*)   (ws + (24u << 20));      // 328 KB

    wconv_k<<<192, 256, 0, stream>>>(wq, wk, wv, wh);
    qkv_k<<<512, 256, 0, stream>>>(x, wh, qhp, khp, vtp);
    attn_k<<<640, 256, 0, stream>>>(qhp, khp, vtp, part, stat, (float*)d_out);
    comb_k<<<192, 256, 0, stream>>>(part, stat, (float*)d_out);
}